// Round 13
// baseline (640.008 us; speedup 1.0000x reference)
//
#include <hip/hip_runtime.h>

#define N 8192
#define L 13
#define SEGS 8
#define NSP 32   // (N/SEGS)/32 K-subtile pairs per seg

typedef _Float16 f16x8 __attribute__((ext_vector_type(8)));
typedef _Float16 f16x2 __attribute__((ext_vector_type(2)));
typedef float f32x4 __attribute__((ext_vector_type(4)));
union F16x8U { f16x8 v; f16x2 h[4]; };

#define C1 (-0.72134752044448f)   // -0.5/ln2
#define C2 (1.44269504088896f)    // log2(e)
#define EBIAS 6.0f                // e' = exp2(C2*x - EBIAS); scale cancels in e'/D'

// smem carve (floats): buf 13*256 | nrm 128 | sAB 2*64*13 | m1s 169 | m2s 169 | ebuf 832
#define SM_NRM  3328
#define SM_SAB  3456
#define SM_M1   5120
#define SM_M2   5289
#define SM_EBUF 5458
#define SMEMW   6290

struct PP {
  const float *points, *logits, *Ws, *Wb, *Cm;
  float *cur, *crd, *snx, *snf, *M1, *M2, *part0, *part1;
  unsigned short *psh, *pbh, *qp0, *qp1, *a1;
  int *cnt;  // [5][128] fan-in counters, zeroed by prep block 32
};

// a1 [spair(256)][lane(64)][j(8)] f16 — A-frags (k-side quintuple/octuple).
// qp [kc(256)][lane=g*16+col][j(8)] f16 = e'[kc*32+phys(g,j)][col]; col13=1.0, col14/15=0.
// psh/pbh: f16 partials [seg][point][16] (13 labels + norm@13 + pad).

__global__ __launch_bounds__(256) void prep_kernel(PP P) {
  int t = threadIdx.x;
  if (blockIdx.x == 32) {  // mprep + counter zeroing
    if (t < L * L) {
      int r = t / L, c = t % L;
      float a = 0.f, b = 0.f;
      for (int j = 0; j < L; ++j) {
        a += P.Cm[r * L + j] * P.Ws[j * L + c];
        b += P.Cm[r * L + j] * P.Wb[j * L + c];
      }
      P.M1[t] = a; P.M2[t] = b;
    }
    for (int i = t; i < 5 * 128; i += 256) P.cnt[i] = 0;
    return;
  }
  int p = blockIdx.x * 256 + t;
  float c6[6];
#pragma unroll
  for (int d = 0; d < 6; ++d) { c6[d] = P.points[p * 6 + d]; P.crd[d * N + p] = c6[d]; }
  float sx = c6[0] * c6[0] + c6[1] * c6[1] + c6[2] * c6[2];
  float sf = c6[3] * c6[3] + c6[4] * c6[4] + c6[5] * c6[5];
  P.snx[p] = sx; P.snf[p] = sf;

  int spair = p >> 5, w = p & 31, rm = w & 15;
  int laneS = (w < 16 ? 0 : 32) + rm;
  int laneB = (w < 16 ? 16 : 48) + rm;
  f16x8 vs = { (_Float16)c6[0], (_Float16)c6[1], (_Float16)c6[2],
               (_Float16)sx, (_Float16)1.0f, (_Float16)0.0f, (_Float16)0.0f, (_Float16)0.0f };
  f16x8 vb = { (_Float16)c6[0], (_Float16)c6[1], (_Float16)c6[2],
               (_Float16)c6[3], (_Float16)c6[4], (_Float16)c6[5],
               (_Float16)(sx + sf), (_Float16)1.0f };
  ((f16x8*)P.a1)[(size_t)spair * 64 + laneS] = vs;
  ((f16x8*)P.a1)[(size_t)spair * 64 + laneB] = vb;

  int kc = p >> 5, kk = p & 31;
  int g = (kk < 16) ? (kk >> 2) : ((kk - 16) >> 2);
  int j2 = (kk < 16) ? (kk & 3) : (4 + (kk & 3));
  size_t qb = ((size_t)kc * 64 + g * 16) * 8 + j2;
  P.qp0[qb + 13 * 8] = 0x3C00;  // f16 1.0 (norm column)
  P.qp0[qb + 14 * 8] = 0;
  P.qp0[qb + 15 * 8] = 0;
  P.qp1[qb + 13 * 8] = 0x3C00;
  P.qp1[qb + 14 * 8] = 0;
  P.qp1[qb + 15 * 8] = 0;

  // initial unnormalized-softmax pack + per-block label sums
  __shared__ float buf[13][256];
#pragma unroll
  for (int l = 0; l < L; ++l) {
    float e = __builtin_amdgcn_exp2f(P.logits[p * L + l] * C2 - EBIAS);
    _Float16 h = (_Float16)e;
    P.qp0[qb + (size_t)l * 8] = *(unsigned short*)&h;
    buf[l][t] = e;
  }
  __syncthreads();
  for (int s = 128; s >= 1; s >>= 1) {
    if (t < s) {
#pragma unroll
      for (int l = 0; l < L; ++l) buf[l][t] += buf[l][t + s];
    }
    __syncthreads();
  }
  if (t < L) P.part0[blockIdx.x * 16 + t] = buf[t][0];
}

#define PK(dst, va, vb_) { auto _r = __builtin_amdgcn_cvt_pkrtz(va, vb_); dst = *(f16x2*)&_r; }
#define E(x) __builtin_amdgcn_exp2f(x)
#define MFMA16(a_, b_, c_) __builtin_amdgcn_mfma_f32_16x16x32_f16(a_, b_, c_, 0, 0, 0)

// 64-point redmix for group bx (round-12-verified body)
__device__ __forceinline__ void redmix_body(const PP& P, int bx, int t,
                                            const float* __restrict__ partin,
                                            float* __restrict__ partout,
                                            unsigned short* __restrict__ qpout,
                                            int R, int last, float* smem) {
  float (*buf)[256] = (float(*)[256])smem;
  float* nrm = smem + SM_NRM;
  float (*sAB)[64][13] = (float(*)[64][13])(smem + SM_SAB);
  float* m1s = smem + SM_M1;
  float* m2s = smem + SM_M2;
  float* ebuf = smem + SM_EBUF;

#pragma unroll
  for (int l = 0; l < L; ++l) buf[l][t] = (t < R) ? partin[t * 16 + l] : 0.f;
  if (t < 169) { m1s[t] = P.M1[t]; m2s[t] = P.M2[t]; }
  __syncthreads();
  for (int s = 128; s >= 1; s >>= 1) {
    if (t < s) {
#pragma unroll
      for (int l = 0; l < L; ++l) buf[l][t] += buf[l][t + s];
    }
    __syncthreads();
  }

  // phase A: t -> (pi 0..63, src, half); f16x8 seg-sums
  int pi = t >> 2, src = (t >> 1) & 1, half = t & 1;
  int p = bx * 64 + pi;
  const unsigned short* basep = src ? P.pbh : P.psh;
  float a8[8] = {0.f, 0.f, 0.f, 0.f, 0.f, 0.f, 0.f, 0.f};
#pragma unroll
  for (int seg = 0; seg < SEGS; ++seg) {
    f16x8 v = *(const f16x8*)(basep + ((size_t)seg * N + p) * 16 + half * 8);
#pragma unroll
    for (int j = 0; j < 8; ++j) a8[j] += (float)v[j];
  }
  if (half) nrm[pi * 2 + src] = a8[5];  // col 13 = norm
  __syncthreads();
  {
    float inv_norm = 1.0f / nrm[pi * 2 + src];
#pragma unroll
    for (int j = 0; j < 8; ++j) {
      int col = half * 8 + j;
      if (col < L) sAB[src][pi][col] = a8[j] * (1.0f / buf[col][0]) * inv_norm;
    }
  }
  __syncthreads();

  // phase B: 13x64 outputs
  for (int oi = t; oi < 832; oi += 256) {
    int r = oi >> 6, ci = oi & 63;
    float v = 0.f;
#pragma unroll
    for (int j = 0; j < L; ++j) {
      v = fmaf(m1s[r * L + j], sAB[0][ci][j], v);
      v = fmaf(m2s[r * L + j], sAB[1][ci][j], v);
    }
    int i = (r << 13) + bx * 64 + ci;
    float o = v + P.logits[i];
    if (last) {
      P.cur[i] = o;
    } else {
      float e = __builtin_amdgcn_exp2f(o * C2 - EBIAS);
      ebuf[oi] = e;
      unsigned int pr = (unsigned int)i / 13u;
      int l = i - pr * 13;
      int kc = pr >> 5, kk = pr & 31;
      int g = (kk < 16) ? (kk >> 2) : ((kk - 16) >> 2);
      int j2 = (kk < 16) ? (kk & 3) : (4 + (kk & 3));
      _Float16 h = (_Float16)e;
      qpout[((size_t)kc * 64 + g * 16 + l) * 8 + j2] = *(unsigned short*)&h;
    }
  }
  if (last) return;
  __syncthreads();

  // label sums -> part rows 2bx, 2bx+1; flat%13 = (2r + bx*64 + ci) % 13
  if (t < 26) {
    int g = (t >= 13) ? 1 : 0, l = t - g * 13;
    int lo = g * 32, hi = lo + 32;
    float s_ = 0.f;
#pragma unroll
    for (int r = 0; r < L; ++r) {
      int base = ((l - 2 * r - bx * 64) % 13 + 26) % 13;
#pragma unroll
      for (int m = 0; m < 5; ++m) {
        int ci = base + 13 * m;
        if (ci >= lo && ci < hi) s_ += ebuf[r * 64 + ci];
      }
    }
    partout[(2 * bx + g) * 16 + l] = s_;
  }
}

// filter (round-5-verified inner loop) + within-launch fan-in redmix tail
__global__ __launch_bounds__(256) void filterfused(PP P, int it) {
  __shared__ float smem[SMEMW];
  __shared__ int flag;
  int tid = threadIdx.x;
  int bx = blockIdx.x, seg = blockIdx.y;

  const unsigned short* qpin = (it & 1) ? P.qp1 : P.qp0;
  unsigned short* qpout = (it & 1) ? P.qp0 : P.qp1;
  const float* partin = (it & 1) ? P.part1 : P.part0;
  float* partout = (it & 1) ? P.part0 : P.part1;
  int R = (it == 0) ? 32 : 256;
  int last = (it == 4);

  {
    int lane = tid & 63, wave = tid >> 6;
    int g = lane >> 4, rm = lane & 15;
    int ptile = bx * 64 + wave * 16;
    int p = ptile + rm;

    float x0 = P.crd[p], x1 = P.crd[N + p], x2 = P.crd[2 * N + p];
    float f0 = P.crd[3 * N + p], f1 = P.crd[4 * N + p], f2 = P.crd[5 * N + p];
    float sx = P.snx[p], sf = P.snf[p];

    f16x8 spat = { (_Float16)(C2 * x0), (_Float16)(C2 * x1), (_Float16)(C2 * x2),
                   (_Float16)C1, (_Float16)(C1 * sx),
                   (_Float16)0.0f, (_Float16)0.0f, (_Float16)0.0f };
    f16x8 bil  = { (_Float16)(C2 * x0), (_Float16)(C2 * x1), (_Float16)(C2 * x2),
                   (_Float16)(C2 * f0), (_Float16)(C2 * f1), (_Float16)(C2 * f2),
                   (_Float16)C1, (_Float16)(C1 * (sx + sf)) };
    f16x8 z8 = {0, 0, 0, 0, 0, 0, 0, 0};
    f16x8 Bs0 = (g == 0) ? spat : z8;
    f16x8 Bb0 = (g == 1) ? bil : z8;
    f16x8 Bs1 = (g == 2) ? spat : z8;
    f16x8 Bb1 = (g == 3) ? bil : z8;

    f32x4 acc_s = {0.f, 0.f, 0.f, 0.f};
    f32x4 acc_b = {0.f, 0.f, 0.f, 0.f};
    const f32x4 zero = {0.f, 0.f, 0.f, 0.f};
    const f16x8* a1 = (const f16x8*)P.a1;
    const f16x8* qp = (const f16x8*)qpin;

    int sp0 = seg * NSP;
#pragma unroll 2
    for (int sp = sp0; sp < sp0 + NSP; ++sp) {
      f16x8 A  = a1[(size_t)sp * 64 + lane];
      f16x8 bq = qp[(size_t)sp * 64 + lane];
      f32x4 ax0 = MFMA16(A, Bs0, zero);
      f32x4 ab0 = MFMA16(A, Bb0, zero);
      f32x4 ax1 = MFMA16(A, Bs1, zero);
      f32x4 ab1 = MFMA16(A, Bb1, zero);
      F16x8U us, ub;
      PK(us.h[0], E(ax0[0]), E(ax0[1]));
      PK(us.h[1], E(ax0[2]), E(ax0[3]));
      PK(us.h[2], E(ax1[0]), E(ax1[1]));
      PK(us.h[3], E(ax1[2]), E(ax1[3]));
      PK(ub.h[0], E(ab0[0]), E(ab0[1]));
      PK(ub.h[1], E(ab0[2]), E(ab0[3]));
      PK(ub.h[2], E(ab1[0]), E(ab1[1]));
      PK(ub.h[3], E(ab1[2]), E(ab1[3]));
      acc_s = MFMA16(us.v, bq, acc_s);
      acc_b = MFMA16(ub.v, bq, acc_b);
    }

    int pout = ptile + g * 4;
    size_t base = ((size_t)seg * N + pout) * 16 + rm;
#pragma unroll
    for (int r = 0; r < 4; ++r) {
      _Float16 hs = (_Float16)acc_s[r];
      _Float16 hb = (_Float16)acc_b[r];
      P.psh[base + (size_t)r * 16] = *(unsigned short*)&hs;
      P.pbh[base + (size_t)r * 16] = *(unsigned short*)&hb;
    }
  }

  // fan-in: release writes, count arrivals; last of the 8 seg-blocks runs redmix
  __threadfence();
  __syncthreads();
  if (tid == 0) flag = (atomicAdd(&P.cnt[it * 128 + bx], 1) == SEGS - 1) ? 1 : 0;
  __syncthreads();
  if (!flag) return;
  __threadfence();  // acquire

  redmix_body(P, bx, tid, partin, partout, qpout, R, last, smem);
}

extern "C" void kernel_launch(void* const* d_in, const int* in_sizes, int n_in,
                              void* d_out, int out_size, void* d_ws, size_t ws_size,
                              hipStream_t stream) {
  PP P;
  P.points = (const float*)d_in[0];
  P.logits = (const float*)d_in[1];
  P.Ws = (const float*)d_in[2];
  P.Wb = (const float*)d_in[3];
  P.Cm = (const float*)d_in[4];
  P.cur = (float*)d_out;

  char* base = (char*)d_ws;
  P.cnt = (int*)base;  base += 4096;
  float* w = (float*)base;
  P.crd  = w;   w += 6 * N;
  P.snx  = w;   w += N;
  P.snf  = w;   w += N;
  P.M1   = w;   w += 256;
  P.M2   = w;   w += 256;
  P.part0 = w;  w += 256 * 16;
  P.part1 = w;  w += 256 * 16;
  unsigned short* u = (unsigned short*)w;
  P.psh = u;  u += (size_t)SEGS * N * 16;   // 4.2 MB
  P.pbh = u;  u += (size_t)SEGS * N * 16;   // 4.2 MB
  P.qp0 = u;  u += (size_t)256 * 64 * 8;    // 256 KB
  P.qp1 = u;  u += (size_t)256 * 64 * 8;    // 256 KB
  P.a1  = u;  u += (size_t)256 * 64 * 8;    // 256 KB

  prep_kernel<<<33, 256, 0, stream>>>(P);
  for (int it = 0; it < 5; ++it)
    filterfused<<<dim3(N / 64, SEGS), 256, 0, stream>>>(P, it);
}

// Round 14
// 150.426 us; speedup vs baseline: 4.2546x; 4.2546x over previous
//
#include <hip/hip_runtime.h>

#define N 8192
#define L 13
#define SEGS 8
#define NSP 32   // k-subtile pairs per seg (32k each)

typedef _Float16 f16x8 __attribute__((ext_vector_type(8)));
typedef _Float16 f16x2 __attribute__((ext_vector_type(2)));
typedef float f32x4 __attribute__((ext_vector_type(4)));
union F16x8U { f16x8 v; f16x2 h[4]; };

#define C1 (-0.72134752044448f)   // -0.5/ln2
#define C2 (1.44269504088896f)    // log2(e)
#define EBIAS 6.0f                // e' = exp2(C2*x - EBIAS); scale cancels in e'/D'

// a1pack [spair(256)][lane(64)][j(8)] f16 — A-frags (k-side quintuple/octuple).
// qpack  [kc(256)][lane=g*16+col][j(8)] f16 = e'[kc*32+phys(g,j)][col]; col13=1.0, col14/15=0.
// psh/pbh: f16 partials [seg][point][16] (13 labels + norm@13 + pad).
// part   [row][16] f32: per-block unnormalized softmax label sums.

__global__ __launch_bounds__(256) void prep_kernel(const float* __restrict__ points,
                                                   const float* __restrict__ logits,
                                                   const float* __restrict__ Ws,
                                                   const float* __restrict__ Wb,
                                                   const float* __restrict__ Cm,
                                                   float* __restrict__ crd,
                                                   float* __restrict__ snx,
                                                   float* __restrict__ snf,
                                                   float* __restrict__ part,
                                                   float* __restrict__ M1,
                                                   float* __restrict__ M2,
                                                   unsigned short* __restrict__ a1pack,
                                                   unsigned short* __restrict__ qpack) {
  int t = threadIdx.x;
  if (blockIdx.x == 32) {  // fused mprep
    if (t < L * L) {
      int r = t / L, c = t % L;
      float a = 0.f, b = 0.f;
      for (int j = 0; j < L; ++j) {
        a += Cm[r * L + j] * Ws[j * L + c];
        b += Cm[r * L + j] * Wb[j * L + c];
      }
      M1[t] = a; M2[t] = b;
    }
    return;
  }
  int p = blockIdx.x * 256 + t;
  float c6[6];
#pragma unroll
  for (int d = 0; d < 6; ++d) { c6[d] = points[p * 6 + d]; crd[d * N + p] = c6[d]; }
  float sx = c6[0] * c6[0] + c6[1] * c6[1] + c6[2] * c6[2];
  float sf = c6[3] * c6[3] + c6[4] * c6[4] + c6[5] * c6[5];
  snx[p] = sx; snf[p] = sf;

  int spair = p >> 5, w = p & 31, rm = w & 15;
  int laneS = (w < 16 ? 0 : 32) + rm;
  int laneB = (w < 16 ? 16 : 48) + rm;
  f16x8 vs = { (_Float16)c6[0], (_Float16)c6[1], (_Float16)c6[2],
               (_Float16)sx, (_Float16)1.0f, (_Float16)0.0f, (_Float16)0.0f, (_Float16)0.0f };
  f16x8 vb = { (_Float16)c6[0], (_Float16)c6[1], (_Float16)c6[2],
               (_Float16)c6[3], (_Float16)c6[4], (_Float16)c6[5],
               (_Float16)(sx + sf), (_Float16)1.0f };
  ((f16x8*)a1pack)[(size_t)spair * 64 + laneS] = vs;
  ((f16x8*)a1pack)[(size_t)spair * 64 + laneB] = vb;

  int kc = p >> 5, kk = p & 31;
  int g = (kk < 16) ? (kk >> 2) : ((kk - 16) >> 2);
  int j2 = (kk < 16) ? (kk & 3) : (4 + (kk & 3));
  size_t qb = ((size_t)kc * 64 + g * 16) * 8 + j2;
  qpack[qb + 13 * 8] = 0x3C00;  // f16 1.0 (norm column)
  qpack[qb + 14 * 8] = 0;
  qpack[qb + 15 * 8] = 0;

  // initial unnormalized-softmax pack + per-block label sums
  __shared__ float buf[13][256];
#pragma unroll
  for (int l = 0; l < L; ++l) {
    float e = __builtin_amdgcn_exp2f(logits[p * L + l] * C2 - EBIAS);
    _Float16 h = (_Float16)e;
    qpack[qb + (size_t)l * 8] = *(unsigned short*)&h;
    buf[l][t] = e;
  }
  __syncthreads();
  for (int s = 128; s >= 1; s >>= 1) {
    if (t < s) {
#pragma unroll
      for (int l = 0; l < L; ++l) buf[l][t] += buf[l][t + s];
    }
    __syncthreads();
  }
  if (t < L) part[blockIdx.x * 16 + t] = buf[t][0];
}

#define PK(dst, va, vb_) { auto _r = __builtin_amdgcn_cvt_pkrtz(va, vb_); dst = *(f16x2*)&_r; }
#define E(x) __builtin_amdgcn_exp2f(x)
#define MFMA16(a_, b_, c_) __builtin_amdgcn_mfma_f32_16x16x32_f16(a_, b_, c_, 0, 0, 0)

// hot kernel: 4 independent waves/block, 16 p-rows each.
// Batch-2 body: 8 dot-MFMAs, then a 32-exp trans block, then 4 acc-MFMAs.
__global__ __launch_bounds__(256) void filter_kernel(const float* __restrict__ crd,
                                                     const float* __restrict__ snx,
                                                     const float* __restrict__ snf,
                                                     const unsigned short* __restrict__ a1pack,
                                                     const unsigned short* __restrict__ qpack,
                                                     unsigned short* __restrict__ psh,
                                                     unsigned short* __restrict__ pbh) {
  int tid = threadIdx.x;
  int lane = tid & 63, wave = tid >> 6;
  int g = lane >> 4, rm = lane & 15;
  int ptile = blockIdx.x * 64 + wave * 16;
  int p = ptile + rm;
  int seg = blockIdx.y;

  float x0 = crd[p], x1 = crd[N + p], x2 = crd[2 * N + p];
  float f0 = crd[3 * N + p], f1 = crd[4 * N + p], f2 = crd[5 * N + p];
  float sx = snx[p], sf = snf[p];

  f16x8 spat = { (_Float16)(C2 * x0), (_Float16)(C2 * x1), (_Float16)(C2 * x2),
                 (_Float16)C1, (_Float16)(C1 * sx),
                 (_Float16)0.0f, (_Float16)0.0f, (_Float16)0.0f };
  f16x8 bil  = { (_Float16)(C2 * x0), (_Float16)(C2 * x1), (_Float16)(C2 * x2),
                 (_Float16)(C2 * f0), (_Float16)(C2 * f1), (_Float16)(C2 * f2),
                 (_Float16)C1, (_Float16)(C1 * (sx + sf)) };
  f16x8 z8 = {0, 0, 0, 0, 0, 0, 0, 0};
  f16x8 Bs0 = (g == 0) ? spat : z8;
  f16x8 Bb0 = (g == 1) ? bil : z8;
  f16x8 Bs1 = (g == 2) ? spat : z8;
  f16x8 Bb1 = (g == 3) ? bil : z8;

  f32x4 acc_s = {0.f, 0.f, 0.f, 0.f};
  f32x4 acc_b = {0.f, 0.f, 0.f, 0.f};
  const f32x4 zero = {0.f, 0.f, 0.f, 0.f};
  const f16x8* a1 = (const f16x8*)a1pack;
  const f16x8* qp = (const f16x8*)qpack;

  int sp0 = seg * NSP;
  for (int sp = sp0; sp < sp0 + NSP; sp += 2) {
    f16x8 A0 = a1[(size_t)sp * 64 + lane];
    f16x8 q0 = qp[(size_t)sp * 64 + lane];
    f16x8 A1 = a1[(size_t)(sp + 1) * 64 + lane];
    f16x8 q1 = qp[(size_t)(sp + 1) * 64 + lane];

    f32x4 xa = MFMA16(A0, Bs0, zero);
    f32x4 ba = MFMA16(A0, Bb0, zero);
    f32x4 xb = MFMA16(A0, Bs1, zero);
    f32x4 bb = MFMA16(A0, Bb1, zero);
    f32x4 xc = MFMA16(A1, Bs0, zero);
    f32x4 bc = MFMA16(A1, Bb0, zero);
    f32x4 xd = MFMA16(A1, Bs1, zero);
    f32x4 bd = MFMA16(A1, Bb1, zero);

    F16x8U us0, ub0, us1, ub1;
    PK(us0.h[0], E(xa[0]), E(xa[1]));
    PK(us0.h[1], E(xa[2]), E(xa[3]));
    PK(us0.h[2], E(xb[0]), E(xb[1]));
    PK(us0.h[3], E(xb[2]), E(xb[3]));
    PK(ub0.h[0], E(ba[0]), E(ba[1]));
    PK(ub0.h[1], E(ba[2]), E(ba[3]));
    PK(ub0.h[2], E(bb[0]), E(bb[1]));
    PK(ub0.h[3], E(bb[2]), E(bb[3]));
    PK(us1.h[0], E(xc[0]), E(xc[1]));
    PK(us1.h[1], E(xc[2]), E(xc[3]));
    PK(us1.h[2], E(xd[0]), E(xd[1]));
    PK(us1.h[3], E(xd[2]), E(xd[3]));
    PK(ub1.h[0], E(bc[0]), E(bc[1]));
    PK(ub1.h[1], E(bc[2]), E(bc[3]));
    PK(ub1.h[2], E(bd[0]), E(bd[1]));
    PK(ub1.h[3], E(bd[2]), E(bd[3]));

    acc_s = MFMA16(us0.v, q0, acc_s);
    acc_b = MFMA16(ub0.v, q0, acc_b);
    acc_s = MFMA16(us1.v, q1, acc_s);
    acc_b = MFMA16(ub1.v, q1, acc_b);
  }

  // D layout: col(lane&15) = label slot, row = 4*(lane>>4)+r = p offset
  int pout = ptile + g * 4;
  size_t base = ((size_t)seg * N + pout) * 16 + rm;
#pragma unroll
  for (int r = 0; r < 4; ++r) {
    _Float16 hs = (_Float16)acc_s[r];
    _Float16 hb = (_Float16)acc_b[r];
    psh[base + (size_t)r * 16] = *(unsigned short*)&hs;
    pbh[base + (size_t)r * 16] = *(unsigned short*)&hb;
  }
}

// fused reduce+mix: 256 blocks, each owns 32 points (all labels).
__global__ __launch_bounds__(256) void redmix_kernel(const unsigned short* __restrict__ psh,
                                                     const unsigned short* __restrict__ pbh,
                                                     float* __restrict__ part,
                                                     const float* __restrict__ M1,
                                                     const float* __restrict__ M2,
                                                     const float* __restrict__ logits,
                                                     float* __restrict__ cur,
                                                     unsigned short* __restrict__ qpack,
                                                     int R, int last) {
  int t = threadIdx.x;
  __shared__ float buf[13][256];
  __shared__ float nrm[64];
  __shared__ float sAB[2][32][13];
  __shared__ float m1s[169], m2s[169];
  __shared__ float ebuf[416];

#pragma unroll
  for (int l = 0; l < L; ++l) buf[l][t] = (t < R) ? part[t * 16 + l] : 0.f;
  if (t < 169) { m1s[t] = M1[t]; m2s[t] = M2[t]; }
  __syncthreads();
  for (int s = 128; s >= 1; s >>= 1) {
    if (t < s) {
#pragma unroll
      for (int l = 0; l < L; ++l) buf[l][t] += buf[l][t + s];
    }
    __syncthreads();
  }

  // phase A: tasks (t<128) = (pi, src, half); f16x8 loads over 8 segs
  int pi = t >> 2, src = (t >> 1) & 1, half = t & 1;
  float a8[8] = {0.f, 0.f, 0.f, 0.f, 0.f, 0.f, 0.f, 0.f};
  if (t < 128) {
    int p = blockIdx.x * 32 + pi;
    const unsigned short* basep = src ? pbh : psh;
#pragma unroll
    for (int seg = 0; seg < SEGS; ++seg) {
      f16x8 v = *(const f16x8*)(basep + ((size_t)seg * N + p) * 16 + half * 8);
#pragma unroll
      for (int j = 0; j < 8; ++j) a8[j] += (float)v[j];
    }
    if (half == 1) nrm[pi * 2 + src] = a8[5];  // col 13 = norm
  }
  __syncthreads();
  if (t < 128) {
    float inv_norm = 1.0f / nrm[pi * 2 + src];
#pragma unroll
    for (int j = 0; j < 8; ++j) {
      int col = half * 8 + j;
      if (col < L) sAB[src][pi][col] = a8[j] * (1.0f / buf[col][0]) * inv_norm;
    }
  }
  __syncthreads();

  // phase B: mix outputs for c in [p0, p0+32), r in [0,13)
  int p0 = blockIdx.x * 32;
#pragma unroll 2
  for (int oi = t; oi < 416; oi += 256) {
    int r = oi >> 5, ci = oi & 31;
    float v = 0.f;
#pragma unroll
    for (int j = 0; j < L; ++j) {
      v = fmaf(m1s[r * L + j], sAB[0][ci][j], v);
      v = fmaf(m2s[r * L + j], sAB[1][ci][j], v);
    }
    int i = (r << 13) + p0 + ci;
    float o = v + logits[i];
    cur[i] = o;
    if (!last) {
      float e = __builtin_amdgcn_exp2f(o * C2 - EBIAS);
      ebuf[oi] = e;
      unsigned int pr = (unsigned int)i / 13u;
      int l = i - pr * 13;
      int kc = pr >> 5, kk = pr & 31;
      int g = (kk < 16) ? (kk >> 2) : ((kk - 16) >> 2);
      int j2 = (kk < 16) ? (kk & 3) : (4 + (kk & 3));
      _Float16 h = (_Float16)e;
      qpack[((size_t)kc * 64 + g * 16 + l) * 8 + j2] = *(unsigned short*)&h;
    }
  }
  if (last) return;
  __syncthreads();

  // label sums of ebuf: flat%13 = (2r + p0 + ci) % 13  (8192 mod 13 == 2)
  if (t < L) {
    float s_ = 0.f;
#pragma unroll
    for (int r = 0; r < L; ++r) {
      int base = (t - p0 - 2 * r) % 13;
      base = (base + 13) % 13;
      float a0 = ebuf[r * 32 + base];
      float a1_ = (base + 13 < 32) ? ebuf[r * 32 + base + 13] : 0.f;
      float a2 = (base + 26 < 32) ? ebuf[r * 32 + base + 26] : 0.f;
      s_ += a0 + a1_ + a2;
    }
    part[blockIdx.x * 16 + t] = s_;
  }
}

extern "C" void kernel_launch(void* const* d_in, const int* in_sizes, int n_in,
                              void* d_out, int out_size, void* d_ws, size_t ws_size,
                              hipStream_t stream) {
  const float* points = (const float*)d_in[0];
  const float* logits = (const float*)d_in[1];
  const float* Ws = (const float*)d_in[2];
  const float* Wb = (const float*)d_in[3];
  const float* Cm = (const float*)d_in[4];

  float* cur = (float*)d_out;

  float* w = (float*)d_ws;
  float* crd  = w;                        w += 6 * N;
  float* snx  = w;                        w += N;
  float* snf  = w;                        w += N;
  float* M1   = w;                        w += 256;
  float* M2   = w;                        w += 256;
  float* part = w;                        w += 256 * 16;
  unsigned short* psh = (unsigned short*)w;                 // SEGS*N*16 u16 = 4.2 MB
  unsigned short* pbh = psh + (size_t)SEGS * N * 16;        // 4.2 MB
  unsigned short* a1pack = pbh + (size_t)SEGS * N * 16;     // 256 KB
  unsigned short* qpack  = a1pack + (size_t)256 * 64 * 8;   // 256 KB

  prep_kernel<<<33, 256, 0, stream>>>(points, logits, Ws, Wb, Cm, crd, snx, snf,
                                      part, M1, M2, a1pack, qpack);

  for (int it = 0; it < 5; ++it) {
    filter_kernel<<<dim3(N / 64, SEGS), 256, 0, stream>>>(crd, snx, snf, a1pack, qpack, psh, pbh);
    redmix_kernel<<<256, 256, 0, stream>>>(psh, pbh, part, M1, M2, logits, cur, qpack,
                                           it == 0 ? 32 : 256, it == 4 ? 1 : 0);
  }
}

// Round 15
// 148.147 us; speedup vs baseline: 4.3201x; 1.0154x over previous
//
#include <hip/hip_runtime.h>

#define N 8192
#define L 13
#define SEGS 8
#define NSP 32   // k-subtile pairs per seg (32k each)

typedef _Float16 f16x8 __attribute__((ext_vector_type(8)));
typedef _Float16 f16x2 __attribute__((ext_vector_type(2)));
typedef float f32x4 __attribute__((ext_vector_type(4)));
union F16x8U { f16x8 v; f16x2 h[4]; };

#define C1 (-0.72134752044448f)   // -0.5/ln2
#define C2 (1.44269504088896f)    // log2(e)
#define EBIAS 6.0f                // e' = exp2(C2*x - EBIAS); scale cancels in e'/D'

// a1pack [spair(256)][lane(64)][j(8)] f16 — A-frags (k-side quintuple/octuple).
// qpack  [kc(256)][lane=g*16+col][j(8)] f16 = e'[kc*32+phys(g,j)][col]; col13=1.0, col14/15=0.
// psh/pbh: f16 partials [seg][point][16] (13 labels + norm@13 + pad).
// part   [row][16] f32: per-block unnormalized softmax label sums.

__global__ __launch_bounds__(256) void prep_kernel(const float* __restrict__ points,
                                                   const float* __restrict__ logits,
                                                   const float* __restrict__ Ws,
                                                   const float* __restrict__ Wb,
                                                   const float* __restrict__ Cm,
                                                   float* __restrict__ crd,
                                                   float* __restrict__ snx,
                                                   float* __restrict__ snf,
                                                   float* __restrict__ part,
                                                   float* __restrict__ M1,
                                                   float* __restrict__ M2,
                                                   unsigned short* __restrict__ a1pack,
                                                   unsigned short* __restrict__ qpack) {
  int t = threadIdx.x;
  if (blockIdx.x == 32) {  // fused mprep
    if (t < L * L) {
      int r = t / L, c = t % L;
      float a = 0.f, b = 0.f;
      for (int j = 0; j < L; ++j) {
        a += Cm[r * L + j] * Ws[j * L + c];
        b += Cm[r * L + j] * Wb[j * L + c];
      }
      M1[t] = a; M2[t] = b;
    }
    return;
  }
  int p = blockIdx.x * 256 + t;
  float c6[6];
#pragma unroll
  for (int d = 0; d < 6; ++d) { c6[d] = points[p * 6 + d]; crd[d * N + p] = c6[d]; }
  float sx = c6[0] * c6[0] + c6[1] * c6[1] + c6[2] * c6[2];
  float sf = c6[3] * c6[3] + c6[4] * c6[4] + c6[5] * c6[5];
  snx[p] = sx; snf[p] = sf;

  int spair = p >> 5, w = p & 31, rm = w & 15;
  int laneS = (w < 16 ? 0 : 32) + rm;
  int laneB = (w < 16 ? 16 : 48) + rm;
  f16x8 vs = { (_Float16)c6[0], (_Float16)c6[1], (_Float16)c6[2],
               (_Float16)sx, (_Float16)1.0f, (_Float16)0.0f, (_Float16)0.0f, (_Float16)0.0f };
  f16x8 vb = { (_Float16)c6[0], (_Float16)c6[1], (_Float16)c6[2],
               (_Float16)c6[3], (_Float16)c6[4], (_Float16)c6[5],
               (_Float16)(sx + sf), (_Float16)1.0f };
  ((f16x8*)a1pack)[(size_t)spair * 64 + laneS] = vs;
  ((f16x8*)a1pack)[(size_t)spair * 64 + laneB] = vb;

  int kc = p >> 5, kk = p & 31;
  int g = (kk < 16) ? (kk >> 2) : ((kk - 16) >> 2);
  int j2 = (kk < 16) ? (kk & 3) : (4 + (kk & 3));
  size_t qb = ((size_t)kc * 64 + g * 16) * 8 + j2;
  qpack[qb + 13 * 8] = 0x3C00;  // f16 1.0 (norm column)
  qpack[qb + 14 * 8] = 0;
  qpack[qb + 15 * 8] = 0;

  // initial unnormalized-softmax pack + per-block label sums
  __shared__ float buf[13][256];
#pragma unroll
  for (int l = 0; l < L; ++l) {
    float e = __builtin_amdgcn_exp2f(logits[p * L + l] * C2 - EBIAS);
    _Float16 h = (_Float16)e;
    qpack[qb + (size_t)l * 8] = *(unsigned short*)&h;
    buf[l][t] = e;
  }
  __syncthreads();
  for (int s = 128; s >= 1; s >>= 1) {
    if (t < s) {
#pragma unroll
      for (int l = 0; l < L; ++l) buf[l][t] += buf[l][t + s];
    }
    __syncthreads();
  }
  if (t < L) part[blockIdx.x * 16 + t] = buf[t][0];
}

#define PK(dst, va, vb_) { auto _r = __builtin_amdgcn_cvt_pkrtz(va, vb_); dst = *(f16x2*)&_r; }
#define E(x) __builtin_amdgcn_exp2f(x)
#define MFMA16(a_, b_, c_) __builtin_amdgcn_mfma_f32_16x16x32_f16(a_, b_, c_, 0, 0, 0)

// hot kernel: 4 independent waves/block, 16 p-rows each.
// Batch-2 body; setprio(1) around the 32-exp trans block (T5: independent-wave regime).
__global__ __launch_bounds__(256) void filter_kernel(const float* __restrict__ crd,
                                                     const float* __restrict__ snx,
                                                     const float* __restrict__ snf,
                                                     const unsigned short* __restrict__ a1pack,
                                                     const unsigned short* __restrict__ qpack,
                                                     unsigned short* __restrict__ psh,
                                                     unsigned short* __restrict__ pbh) {
  int tid = threadIdx.x;
  int lane = tid & 63, wave = tid >> 6;
  int g = lane >> 4, rm = lane & 15;
  int ptile = blockIdx.x * 64 + wave * 16;
  int p = ptile + rm;
  int seg = blockIdx.y;

  float x0 = crd[p], x1 = crd[N + p], x2 = crd[2 * N + p];
  float f0 = crd[3 * N + p], f1 = crd[4 * N + p], f2 = crd[5 * N + p];
  float sx = snx[p], sf = snf[p];

  f16x8 spat = { (_Float16)(C2 * x0), (_Float16)(C2 * x1), (_Float16)(C2 * x2),
                 (_Float16)C1, (_Float16)(C1 * sx),
                 (_Float16)0.0f, (_Float16)0.0f, (_Float16)0.0f };
  f16x8 bil  = { (_Float16)(C2 * x0), (_Float16)(C2 * x1), (_Float16)(C2 * x2),
                 (_Float16)(C2 * f0), (_Float16)(C2 * f1), (_Float16)(C2 * f2),
                 (_Float16)C1, (_Float16)(C1 * (sx + sf)) };
  f16x8 z8 = {0, 0, 0, 0, 0, 0, 0, 0};
  f16x8 Bs0 = (g == 0) ? spat : z8;
  f16x8 Bb0 = (g == 1) ? bil : z8;
  f16x8 Bs1 = (g == 2) ? spat : z8;
  f16x8 Bb1 = (g == 3) ? bil : z8;

  f32x4 acc_s = {0.f, 0.f, 0.f, 0.f};
  f32x4 acc_b = {0.f, 0.f, 0.f, 0.f};
  const f32x4 zero = {0.f, 0.f, 0.f, 0.f};
  const f16x8* a1 = (const f16x8*)a1pack;
  const f16x8* qp = (const f16x8*)qpack;

  int sp0 = seg * NSP;
  for (int sp = sp0; sp < sp0 + NSP; sp += 2) {
    f16x8 A0 = a1[(size_t)sp * 64 + lane];
    f16x8 q0 = qp[(size_t)sp * 64 + lane];
    f16x8 A1 = a1[(size_t)(sp + 1) * 64 + lane];
    f16x8 q1 = qp[(size_t)(sp + 1) * 64 + lane];

    f32x4 xa = MFMA16(A0, Bs0, zero);
    f32x4 ba = MFMA16(A0, Bb0, zero);
    f32x4 xb = MFMA16(A0, Bs1, zero);
    f32x4 bb = MFMA16(A0, Bb1, zero);
    f32x4 xc = MFMA16(A1, Bs0, zero);
    f32x4 bc = MFMA16(A1, Bb0, zero);
    f32x4 xd = MFMA16(A1, Bs1, zero);
    f32x4 bd = MFMA16(A1, Bb1, zero);

    __builtin_amdgcn_s_setprio(1);
    F16x8U us0, ub0, us1, ub1;
    PK(us0.h[0], E(xa[0]), E(xa[1]));
    PK(us0.h[1], E(xa[2]), E(xa[3]));
    PK(us0.h[2], E(xb[0]), E(xb[1]));
    PK(us0.h[3], E(xb[2]), E(xb[3]));
    PK(ub0.h[0], E(ba[0]), E(ba[1]));
    PK(ub0.h[1], E(ba[2]), E(ba[3]));
    PK(ub0.h[2], E(bb[0]), E(bb[1]));
    PK(ub0.h[3], E(bb[2]), E(bb[3]));
    PK(us1.h[0], E(xc[0]), E(xc[1]));
    PK(us1.h[1], E(xc[2]), E(xc[3]));
    PK(us1.h[2], E(xd[0]), E(xd[1]));
    PK(us1.h[3], E(xd[2]), E(xd[3]));
    PK(ub1.h[0], E(bc[0]), E(bc[1]));
    PK(ub1.h[1], E(bc[2]), E(bc[3]));
    PK(ub1.h[2], E(bd[0]), E(bd[1]));
    PK(ub1.h[3], E(bd[2]), E(bd[3]));
    __builtin_amdgcn_s_setprio(0);

    acc_s = MFMA16(us0.v, q0, acc_s);
    acc_b = MFMA16(ub0.v, q0, acc_b);
    acc_s = MFMA16(us1.v, q1, acc_s);
    acc_b = MFMA16(ub1.v, q1, acc_b);
  }

  // D layout: col(lane&15) = label slot, row = 4*(lane>>4)+r = p offset
  int pout = ptile + g * 4;
  size_t base = ((size_t)seg * N + pout) * 16 + rm;
#pragma unroll
  for (int r = 0; r < 4; ++r) {
    _Float16 hs = (_Float16)acc_s[r];
    _Float16 hb = (_Float16)acc_b[r];
    psh[base + (size_t)r * 16] = *(unsigned short*)&hs;
    pbh[base + (size_t)r * 16] = *(unsigned short*)&hb;
  }
}

// fused reduce+mix: 256 blocks, each owns 32 points (all labels).
__global__ __launch_bounds__(256) void redmix_kernel(const unsigned short* __restrict__ psh,
                                                     const unsigned short* __restrict__ pbh,
                                                     float* __restrict__ part,
                                                     const float* __restrict__ M1,
                                                     const float* __restrict__ M2,
                                                     const float* __restrict__ logits,
                                                     float* __restrict__ cur,
                                                     unsigned short* __restrict__ qpack,
                                                     int R, int last) {
  int t = threadIdx.x;
  __shared__ float buf[13][256];
  __shared__ float nrm[64];
  __shared__ float sAB[2][32][13];
  __shared__ float m1s[169], m2s[169];
  __shared__ float ebuf[416];

#pragma unroll
  for (int l = 0; l < L; ++l) buf[l][t] = (t < R) ? part[t * 16 + l] : 0.f;
  if (t < 169) { m1s[t] = M1[t]; m2s[t] = M2[t]; }
  __syncthreads();
  for (int s = 128; s >= 1; s >>= 1) {
    if (t < s) {
#pragma unroll
      for (int l = 0; l < L; ++l) buf[l][t] += buf[l][t + s];
    }
    __syncthreads();
  }

  // phase A: tasks (t<128) = (pi, src, half); f16x8 loads over 8 segs
  int pi = t >> 2, src = (t >> 1) & 1, half = t & 1;
  float a8[8] = {0.f, 0.f, 0.f, 0.f, 0.f, 0.f, 0.f, 0.f};
  if (t < 128) {
    int p = blockIdx.x * 32 + pi;
    const unsigned short* basep = src ? pbh : psh;
#pragma unroll
    for (int seg = 0; seg < SEGS; ++seg) {
      f16x8 v = *(const f16x8*)(basep + ((size_t)seg * N + p) * 16 + half * 8);
#pragma unroll
      for (int j = 0; j < 8; ++j) a8[j] += (float)v[j];
    }
    if (half == 1) nrm[pi * 2 + src] = a8[5];  // col 13 = norm
  }
  __syncthreads();
  if (t < 128) {
    float inv_norm = 1.0f / nrm[pi * 2 + src];
#pragma unroll
    for (int j = 0; j < 8; ++j) {
      int col = half * 8 + j;
      if (col < L) sAB[src][pi][col] = a8[j] * (1.0f / buf[col][0]) * inv_norm;
    }
  }
  __syncthreads();

  // phase B: mix outputs for c in [p0, p0+32), r in [0,13)
  int p0 = blockIdx.x * 32;
#pragma unroll 2
  for (int oi = t; oi < 416; oi += 256) {
    int r = oi >> 5, ci = oi & 31;
    float v = 0.f;
#pragma unroll
    for (int j = 0; j < L; ++j) {
      v = fmaf(m1s[r * L + j], sAB[0][ci][j], v);
      v = fmaf(m2s[r * L + j], sAB[1][ci][j], v);
    }
    int i = (r << 13) + p0 + ci;
    float o = v + logits[i];
    cur[i] = o;
    if (!last) {
      float e = __builtin_amdgcn_exp2f(o * C2 - EBIAS);
      ebuf[oi] = e;
      unsigned int pr = (unsigned int)i / 13u;
      int l = i - pr * 13;
      int kc = pr >> 5, kk = pr & 31;
      int g = (kk < 16) ? (kk >> 2) : ((kk - 16) >> 2);
      int j2 = (kk < 16) ? (kk & 3) : (4 + (kk & 3));
      _Float16 h = (_Float16)e;
      qpack[((size_t)kc * 64 + g * 16 + l) * 8 + j2] = *(unsigned short*)&h;
    }
  }
  if (last) return;
  __syncthreads();

  // label sums of ebuf: flat%13 = (2r + p0 + ci) % 13  (8192 mod 13 == 2)
  if (t < L) {
    float s_ = 0.f;
#pragma unroll
    for (int r = 0; r < L; ++r) {
      int base = (t - p0 - 2 * r) % 13;
      base = (base + 13) % 13;
      float a0 = ebuf[r * 32 + base];
      float a1_ = (base + 13 < 32) ? ebuf[r * 32 + base + 13] : 0.f;
      float a2 = (base + 26 < 32) ? ebuf[r * 32 + base + 26] : 0.f;
      s_ += a0 + a1_ + a2;
    }
    part[blockIdx.x * 16 + t] = s_;
  }
}

extern "C" void kernel_launch(void* const* d_in, const int* in_sizes, int n_in,
                              void* d_out, int out_size, void* d_ws, size_t ws_size,
                              hipStream_t stream) {
  const float* points = (const float*)d_in[0];
  const float* logits = (const float*)d_in[1];
  const float* Ws = (const float*)d_in[2];
  const float* Wb = (const float*)d_in[3];
  const float* Cm = (const float*)d_in[4];

  float* cur = (float*)d_out;

  float* w = (float*)d_ws;
  float* crd  = w;                        w += 6 * N;
  float* snx  = w;                        w += N;
  float* snf  = w;                        w += N;
  float* M1   = w;                        w += 256;
  float* M2   = w;                        w += 256;
  float* part = w;                        w += 256 * 16;
  unsigned short* psh = (unsigned short*)w;                 // SEGS*N*16 u16 = 4.2 MB
  unsigned short* pbh = psh + (size_t)SEGS * N * 16;        // 4.2 MB
  unsigned short* a1pack = pbh + (size_t)SEGS * N * 16;     // 256 KB
  unsigned short* qpack  = a1pack + (size_t)256 * 64 * 8;   // 256 KB

  prep_kernel<<<33, 256, 0, stream>>>(points, logits, Ws, Wb, Cm, crd, snx, snf,
                                      part, M1, M2, a1pack, qpack);

  for (int it = 0; it < 5; ++it) {
    filter_kernel<<<dim3(N / 64, SEGS), 256, 0, stream>>>(crd, snx, snf, a1pack, qpack, psh, pbh);
    redmix_kernel<<<256, 256, 0, stream>>>(psh, pbh, part, M1, M2, logits, cur, qpack,
                                           it == 0 ? 32 : 256, it == 4 ? 1 : 0);
  }
}